// Round 7
// baseline (1509.780 us; speedup 1.0000x reference)
//
#include <hip/hip_runtime.h>
#include <hip/hip_bf16.h>

typedef __attribute__((ext_vector_type(8))) short bf16x8;
typedef __attribute__((ext_vector_type(4))) float f32x4;

#define DEVI __device__ __forceinline__

DEVI short f2bf(float f) {
  union { float f; unsigned u; } v; v.f = f;
  unsigned r = v.u + 0x7FFFu + ((v.u >> 16) & 1u);
  return (short)(r >> 16);
}

DEVI float exp2a(float x) { float r; asm("v_exp_f32 %0, %1" : "=v"(r) : "v"(x)); return r; }

DEVI unsigned pk2(float lo, float hi) {
  union { __hip_bfloat162 h; unsigned u; } v;
  float2 f; f.x = lo; f.y = hi;
  v.h = __float22bfloat162_rn(f);
  return v.u;
}

union U8 { unsigned u[4]; bf16x8 v; };
DEVI bf16x8 mk8(unsigned a, unsigned b, unsigned c, unsigned d) {
  U8 x; x.u[0]=a; x.u[1]=b; x.u[2]=c; x.u[3]=d; return x.v;
}

// ---------------- pack kernels ----------------
// wPk fragment-linear: wPk[((h*6+nf)*16+kf)*512 + lane*8 + e] = bf16(w_qkv[k][col])
// k = kf*32 + (lane>>4)*8 + e ; col = (nf>>1)*512 + h*32 + (nf&1)*16 + (lane&15)
__global__ __launch_bounds__(256) void pack_wqkv(const float* __restrict__ w,
                                                 short* __restrict__ wPk) {
  int i = blockIdx.x * 256 + threadIdx.x;      // 786432
  int e = i & 7, lane = (i >> 3) & 63, kf = (i >> 9) & 15, hn = i >> 13;  // hn<96
  int h = hn / 6, nf = hn - h * 6;
  int g = lane >> 4, l15 = lane & 15;
  int k = kf * 32 + g * 8 + e;
  int col = (nf >> 1) * 512 + h * 32 + (nf & 1) * 16 + l15;
  wPk[i] = f2bf(w[k * 1536 + col]);
}

// wpPk: wpPk[(cf*16+kf)*512 + lane*8 + e] = bf16(w_proj[k][col]); col = cf*16+(lane&15)
__global__ __launch_bounds__(256) void pack_wproj(const float* __restrict__ w,
                                                  short* __restrict__ wpPk) {
  int i = blockIdx.x * 256 + threadIdx.x;      // 262144
  int e = i & 7, lane = (i >> 3) & 63, kf = (i >> 9) & 15, cf = i >> 13;  // cf<32
  int g = lane >> 4, l15 = lane & 15;
  int k = kf * 32 + g * 8 + e, col = cf * 16 + l15;
  wpPk[i] = f2bf(w[k * 512 + col]);
}

// biasT[h][m][n] = btab[relidx(n_query, m_key)*16+h] * log2(e); -1e30 for m>=49
__global__ __launch_bounds__(256) void fill_biasT(const float* __restrict__ btab,
                                                  float* __restrict__ biasT) {
  int i = blockIdx.x * 256 + threadIdx.x;      // 16*64*64
  int h = i >> 12, m = (i >> 6) & 63, n = i & 63;
  float v;
  if (m >= 49) {
    v = -1e30f;
  } else {
    int nn = n > 48 ? 48 : n;
    int ni = nn / 7, nj = nn - ni * 7;
    int mi = m / 7,  mj = m - mi * 7;
    int idx = (ni - mi + 6) * 13 + (nj - mj + 6);
    v = btab[idx * 16 + h] * 1.4426950408889634f;
  }
  biasT[i] = v;
}

// ---------------- megakernel: one block per window ----------------
// Phase 1: stage x[b] (49x512 fp32 -> bf16, rows 49-63 = row 48) into As, XOR-swizzled.
// Phase 2 (per wave, 4 heads each): 64x96 GEMM (A from As, W frag-linear from L2) ->
//   +bias -> Q/K/V 12KB wave-local LDS bufs -> swapped-QK^T in-register softmax (r3-verified)
//   -> PV -> O packed bf16 in regs.
// Phase 3: barrier; O -> As (x dead); barrier; proj GEMM from As x wpPk; +b_proj -> d_out.

__global__ __launch_bounds__(256, 1)
void fusedwin(const float* __restrict__ x, const short* __restrict__ wPk,
              const short* __restrict__ wpPk, const float* __restrict__ bqkv,
              const float* __restrict__ bproj, const float* __restrict__ biasT,
              float* __restrict__ out) {
  __shared__ short As[32768];        // 64 KB
  __shared__ short Bufs[4][6144];    // per wave: Q @0, K @2048, V @4096 (shorts)

  const int t = threadIdx.x, lane = t & 63, wv = t >> 6;
  const int l15 = lane & 15, g = lane >> 4, g4 = g * 4;
  const int b = blockIdx.x;

  // ---- phase 1: stage x window
  {
    const float* xw = x + (long)b * 25088;
#pragma unroll
    for (int it = 0; it < 16; ++it) {
      int q = it * 256 + t, row = q >> 6, c = q & 63;
      int sr = row > 48 ? 48 : row;
      const float4* p = (const float4*)(xw + sr * 512 + c * 8);
      float4 a = p[0], d = p[1];
      bf16x8 r;
      r[0] = f2bf(a.x); r[1] = f2bf(a.y); r[2] = f2bf(a.z); r[3] = f2bf(a.w);
      r[4] = f2bf(d.x); r[5] = f2bf(d.y); r[6] = f2bf(d.z); r[7] = f2bf(d.w);
      *(bf16x8*)(As + row * 512 + ((c ^ (row & 7)) * 8)) = r;
    }
  }
  __syncthreads();

  short* Qb = Bufs[wv];
  short* Kb = Qb + 2048;
  short* Vb = Qb + 4096;
  const int x7 = l15 & 7;

  unsigned up[4][4][2][2];   // packed attn-out [hh][j][dt][rpair]

#pragma unroll
  for (int hh = 0; hh < 4; ++hh) {
    const int h = wv * 4 + hh;

    // ---- head GEMM: acc[4][6] = A(64x512) x W_h(512x96)
    f32x4 acc[4][6] = {};
    const short* wp = wPk + (long)(h * 96) * 512 + lane * 8;
#pragma unroll
    for (int kf = 0; kf < 16; ++kf) {
      bf16x8 af[4], wf[6];
#pragma unroll
      for (int mf = 0; mf < 4; ++mf)
        af[mf] = *(const bf16x8*)(As + (mf * 16 + l15) * 512 + (((kf * 4 + g) ^ x7) * 8));
#pragma unroll
      for (int nf = 0; nf < 6; ++nf)
        wf[nf] = *(const bf16x8*)(wp + (nf * 16 + kf) * 512);
#pragma unroll
      for (int mf = 0; mf < 4; ++mf)
#pragma unroll
        for (int nf = 0; nf < 6; ++nf)
          acc[mf][nf] = __builtin_amdgcn_mfma_f32_16x16x32_bf16(af[mf], wf[nf], acc[mf][nf], 0, 0, 0);
    }

    // ---- +bias, write Q/K/V bufs (chunk-swizzled rows of 32 shorts)
#pragma unroll
    for (int nf = 0; nf < 6; ++nf) {
      float bq = bqkv[(nf >> 1) * 512 + h * 32 + (nf & 1) * 16 + l15];
      short* buf = Qb + (nf >> 1) * 2048;
      int d = (nf & 1) * 16 + l15;
      int ch = d >> 3, d7 = d & 7;
#pragma unroll
      for (int mf = 0; mf < 4; ++mf)
#pragma unroll
        for (int r = 0; r < 4; ++r) {
          int row = mf * 16 + g4 + r;
          buf[row * 32 + ((ch ^ (row & 3)) * 8) + d7] = f2bf(acc[mf][nf][r] + bq);
        }
    }

    // ---- attn (verbatim r3 structure, LDS-sourced)
    bf16x8 qf[4], kfr[4];
#pragma unroll
    for (int i2 = 0; i2 < 4; ++i2) {
      int row = i2 * 16 + l15;
      int sl = (g ^ (row & 3)) * 8;
      kfr[i2] = *(const bf16x8*)(Kb + row * 32 + sl);
      qf[i2]  = *(const bf16x8*)(Qb + row * 32 + sl);
    }
    bf16x8 vf[2][2];
#pragma unroll
    for (int kt2 = 0; kt2 < 2; ++kt2)
#pragma unroll
      for (int hi = 0; hi < 2; ++hi)
#pragma unroll
        for (int r = 0; r < 4; ++r) {
          int m = kt2 * 32 + hi * 16 + g4 + r;
#pragma unroll
          for (int dt = 0; dt < 2; ++dt) {
            int d = dt * 16 + l15;
            vf[kt2][dt][hi * 4 + r] = Vb[m * 32 + (((d >> 3) ^ (m & 3)) * 8) + (d & 7)];
          }
        }

    f32x4 s[4][4] = {};
#pragma unroll
    for (int i2 = 0; i2 < 4; ++i2)
#pragma unroll
      for (int j = 0; j < 4; ++j)
        s[i2][j] = __builtin_amdgcn_mfma_f32_16x16x32_bf16(kfr[i2], qf[j], s[i2][j], 0, 0, 0);

    const float* biasH = biasT + h * 4096;
    float sum[4] = {0.f, 0.f, 0.f, 0.f};
#pragma unroll
    for (int i2 = 0; i2 < 4; ++i2)
#pragma unroll
      for (int r = 0; r < 4; ++r) {
        int m = i2 * 16 + g4 + r;
        const float* bp = biasH + m * 64 + l15;
#pragma unroll
        for (int j = 0; j < 4; ++j) {
          float p = exp2a(fmaf(s[i2][j][r], 0.06375871f, bp[j * 16]));
          s[i2][j][r] = p;
          sum[j] += p;
        }
      }
#pragma unroll
    for (int j = 0; j < 4; ++j) {
      sum[j] += __shfl_xor(sum[j], 16);
      sum[j] += __shfl_xor(sum[j], 32);
      sum[j] = 1.f / sum[j];
    }

    unsigned pk[4][4][2];
#pragma unroll
    for (int j = 0; j < 4; ++j)
#pragma unroll
      for (int i2 = 0; i2 < 4; ++i2) {
        pk[j][i2][0] = pk2(s[i2][j][0] * sum[j], s[i2][j][1] * sum[j]);
        pk[j][i2][1] = pk2(s[i2][j][2] * sum[j], s[i2][j][3] * sum[j]);
      }

    f32x4 o[4][2] = {};
#pragma unroll
    for (int j = 0; j < 4; ++j) {
      bf16x8 a0 = mk8(pk[j][0][0], pk[j][0][1], pk[j][1][0], pk[j][1][1]);
      bf16x8 a1 = mk8(pk[j][2][0], pk[j][2][1], pk[j][3][0], pk[j][3][1]);
      o[j][0] = __builtin_amdgcn_mfma_f32_16x16x32_bf16(a0, vf[0][0], o[j][0], 0, 0, 0);
      o[j][0] = __builtin_amdgcn_mfma_f32_16x16x32_bf16(a1, vf[1][0], o[j][0], 0, 0, 0);
      o[j][1] = __builtin_amdgcn_mfma_f32_16x16x32_bf16(a0, vf[0][1], o[j][1], 0, 0, 0);
      o[j][1] = __builtin_amdgcn_mfma_f32_16x16x32_bf16(a1, vf[1][1], o[j][1], 0, 0, 0);
    }
#pragma unroll
    for (int j = 0; j < 4; ++j)
#pragma unroll
      for (int dt = 0; dt < 2; ++dt) {
        up[hh][j][dt][0] = pk2(o[j][dt][0], o[j][dt][1]);
        up[hh][j][dt][1] = pk2(o[j][dt][2], o[j][dt][3]);
      }
  }

  __syncthreads();   // all waves finished reading As (head-GEMMs)

  // ---- attn-out -> As (bf16, swizzled); junk rows finite, fine
#pragma unroll
  for (int hh = 0; hh < 4; ++hh) {
    int h = wv * 4 + hh;
#pragma unroll
    for (int j = 0; j < 4; ++j)
#pragma unroll
      for (int r = 0; r < 4; ++r) {
        int row = j * 16 + g4 + r;
#pragma unroll
        for (int dt = 0; dt < 2; ++dt) {
          int col = h * 32 + dt * 16 + l15;
          short val = (short)(up[hh][j][dt][r >> 1] >> ((r & 1) * 16));
          As[row * 512 + (((col >> 3) ^ (row & 7)) * 8) + (col & 7)] = val;
        }
      }
  }
  __syncthreads();

  // ---- proj GEMM: out[64][512] = AO x Wp; wave owns cols wv*128..+127
  f32x4 a2[4][8] = {};
  const short* wpp = wpPk + (long)(wv * 128) * 512 + lane * 8;
#pragma unroll
  for (int kf = 0; kf < 16; ++kf) {
    bf16x8 af2[4], wf2[8];
#pragma unroll
    for (int mf = 0; mf < 4; ++mf)
      af2[mf] = *(const bf16x8*)(As + (mf * 16 + l15) * 512 + (((kf * 4 + g) ^ x7) * 8));
#pragma unroll
    for (int nf = 0; nf < 8; ++nf)
      wf2[nf] = *(const bf16x8*)(wpp + (nf * 16 + kf) * 512);
#pragma unroll
    for (int mf = 0; mf < 4; ++mf)
#pragma unroll
      for (int nf = 0; nf < 8; ++nf)
        a2[mf][nf] = __builtin_amdgcn_mfma_f32_16x16x32_bf16(af2[mf], wf2[nf], a2[mf][nf], 0, 0, 0);
  }

  float* ob = out + (long)b * 25088;
#pragma unroll
  for (int mf = 0; mf < 4; ++mf)
#pragma unroll
    for (int r = 0; r < 4; ++r) {
      int row = mf * 16 + g4 + r;
      if (row < 49) {
#pragma unroll
        for (int nf = 0; nf < 8; ++nf) {
          int col = wv * 128 + nf * 16 + l15;
          ob[row * 512 + col] = a2[mf][nf][r] + bproj[col];
        }
      }
    }
}

// ---------------- host ----------------

extern "C" void kernel_launch(void* const* d_in, const int* in_sizes, int n_in,
                              void* d_out, int out_size, void* d_ws, size_t ws_size,
                              hipStream_t stream) {
  (void)in_sizes; (void)n_in; (void)out_size; (void)ws_size;
  const float* x      = (const float*)d_in[0];
  const float* w_qkv  = (const float*)d_in[1];
  const float* b_qkv  = (const float*)d_in[2];
  const float* w_proj = (const float*)d_in[3];
  const float* b_proj = (const float*)d_in[4];
  const float* btab   = (const float*)d_in[5];

  char* ws = (char*)d_ws;
  short* wPk   = (short*)ws;                        // 1,572,864 B
  short* wpPk  = (short*)(ws + 1572864L);           //   524,288 B
  float* biasT = (float*)(ws + 1572864L + 524288L); //   262,144 B

  pack_wqkv <<<3072, 256, 0, stream>>>(w_qkv, wPk);
  pack_wproj<<<1024, 256, 0, stream>>>(w_proj, wpPk);
  fill_biasT<<<256, 256, 0, stream>>>(btab, biasT);
  fusedwin  <<<4096, 256, 0, stream>>>(x, wPk, wpPk, b_qkv, b_proj, biasT,
                                       (float*)d_out);
}